// Round 7
// baseline (707.918 us; speedup 1.0000x reference)
//
#include <hip/hip_runtime.h>
#include <stdint.h>

#define N_PTS 8192
#define N_B 8
#define NGROUP 512
#define GSIZE 32
#define BIGF 1e10f

#define K1_THREADS 256
#define K1_PPT 32
#define K1_WAVES 4

#define K2_THREADS 512
#define K2_PPT 16
#define K2_WAVES 8

typedef float f32x2 __attribute__((ext_vector_type(2)));

// ---------------- packed f32 ops (VOP3P) — bit-identical IEEE per half ----------------
__device__ __forceinline__ f32x2 pk_add(f32x2 a, f32x2 b) {
    f32x2 d; asm("v_pk_add_f32 %0, %1, %2" : "=v"(d) : "v"(a), "v"(b)); return d;
}
__device__ __forceinline__ f32x2 pk_sub(f32x2 a, f32x2 b) {
    f32x2 d; asm("v_pk_add_f32 %0, %1, %2 neg_lo:[0,1] neg_hi:[0,1]" : "=v"(d) : "v"(a), "v"(b)); return d;
}
__device__ __forceinline__ f32x2 pk_mul(f32x2 a, f32x2 b) {
    f32x2 d; asm("v_pk_mul_f32 %0, %1, %2" : "=v"(d) : "v"(a), "v"(b)); return d;
}
__device__ __forceinline__ f32x2 pk_fma(f32x2 a, f32x2 b, f32x2 c) {
    f32x2 d; asm("v_pk_fma_f32 %0, %1, %2, %3" : "=v"(d) : "v"(a), "v"(b), "v"(c)); return d;
}

// ---------------- DPP reductions ------------------------------------------------------
#define DPP_RED_STEP_F(ctrl, rmask, op)                                            \
    v = op(v, __int_as_float(__builtin_amdgcn_update_dpp(                          \
            __float_as_int(v), __float_as_int(v), ctrl, rmask, 0xF, false)))

__device__ __forceinline__ float wave_fmax(float v) {
    DPP_RED_STEP_F(0x111, 0xF, fmaxf);
    DPP_RED_STEP_F(0x112, 0xF, fmaxf);
    DPP_RED_STEP_F(0x114, 0xF, fmaxf);
    DPP_RED_STEP_F(0x118, 0xF, fmaxf);
    DPP_RED_STEP_F(0x142, 0xA, fmaxf);
    DPP_RED_STEP_F(0x143, 0xC, fmaxf);
    return v;   // lane 63 valid
}

#define U64_DPP_STEP(ctrl, rmask, CMPOP)                                           \
    { unsigned lo_ = (unsigned)v, hi_ = (unsigned)(v >> 32);                       \
      unsigned olo = (unsigned)__builtin_amdgcn_update_dpp((int)lo_, (int)lo_, ctrl, rmask, 0xF, false); \
      unsigned ohi = (unsigned)__builtin_amdgcn_update_dpp((int)hi_, (int)hi_, ctrl, rmask, 0xF, false); \
      unsigned long long o = ((unsigned long long)ohi << 32) | olo;                \
      if (o CMPOP v) v = o; }

__device__ __forceinline__ unsigned long long wave_u64_min(unsigned long long v) {
    U64_DPP_STEP(0x111, 0xF, <);
    U64_DPP_STEP(0x112, 0xF, <);
    U64_DPP_STEP(0x114, 0xF, <);
    U64_DPP_STEP(0x118, 0xF, <);
    U64_DPP_STEP(0x142, 0xA, <);
    U64_DPP_STEP(0x143, 0xC, <);
    return v;   // lane 63 valid
}

__device__ __forceinline__ int rdlane63_i(int v) {
    return __builtin_amdgcn_readlane(v, 63);
}
__device__ __forceinline__ unsigned long long rdlane_u64(unsigned long long v, int l) {
    unsigned lo = (unsigned)__builtin_amdgcn_readlane((int)(unsigned)v, l);
    unsigned hi = (unsigned)__builtin_amdgcn_readlane((int)(unsigned)(v >> 32), l);
    return ((unsigned long long)hi << 32) | lo;
}

// Exact (no-FMA) squared distance in numpy's evaluation order: (dx^2 + dy^2) + dz^2
__device__ __forceinline__ float sq_dist(float x, float y, float z,
                                         float cx, float cy, float cz) {
    float dx = __fsub_rn(x, cx);
    float dy = __fsub_rn(y, cy);
    float dz = __fsub_rn(z, cz);
    return __fadd_rn(__fadd_rn(__fmul_rn(dx, dx), __fmul_rn(dy, dy)), __fmul_rn(dz, dz));
}

__device__ __forceinline__ unsigned fxform(unsigned u) {
    return u ^ (unsigned)(((int)u >> 31) | 0x80000000);
}

// bitonic sort (ascending) of an N-element register array of u64
template<int N>
__device__ __forceinline__ void bitonic_sort(unsigned long long* a) {
#pragma unroll
    for (int k = 2; k <= N; k <<= 1) {
#pragma unroll
        for (int j = k >> 1; j > 0; j >>= 1) {
#pragma unroll
            for (int i = 0; i < N; ++i) {
                int ixj = i ^ j;
                if (ixj > i) {
                    bool up = ((i & k) == 0);
                    unsigned long long x = a[i], y = a[ixj];
                    bool sw = up ? (x > y) : (x < y);
                    if (sw) { a[i] = y; a[ixj] = x; }
                }
            }
        }
    }
}

// ---------------- Kernel 1: farthest point sampling, one block per batch ---------------
// 256 threads = 4 waves = 1 wave/SIMD: no co-wave issue contention, tiny barrier skew.
extern "C" __global__ __launch_bounds__(K1_THREADS) void fps_kernel(
    const float* __restrict__ xyz, int* __restrict__ fps_idx)
{
    const int b   = blockIdx.x;
    const int tid = threadIdx.x;
    const float* base = xyz + (size_t)b * N_PTS * 6;
    const float4* b4 = (const float4*)base;

    __shared__ float lx[N_PTS], ly[N_PTS], lz[N_PTS];
    __shared__ unsigned part[2][K1_WAVES][8];   // {~idx, distBits, x, y, z, pad...} 32B stride

    // 32 consecutive points per thread via 48 float4 loads (all bytes used)
    float sx[K1_PPT], sy[K1_PPT], sz[K1_PPT], dd[K1_PPT];
    const int tb = tid * 48;
#pragma unroll
    for (int c = 0; c < 8; ++c) {
        float4 f0 = b4[tb + c * 6 + 0];
        float4 f1 = b4[tb + c * 6 + 1];
        float4 f2 = b4[tb + c * 6 + 2];
        float4 f3 = b4[tb + c * 6 + 3];
        float4 f4 = b4[tb + c * 6 + 4];
        float4 f5 = b4[tb + c * 6 + 5];
        sx[c*4+0] = f0.x; sy[c*4+0] = f0.y; sz[c*4+0] = f0.z;
        sx[c*4+1] = f1.z; sy[c*4+1] = f1.w; sz[c*4+1] = f2.x;
        sx[c*4+2] = f3.x; sy[c*4+2] = f3.y; sz[c*4+2] = f3.z;
        sx[c*4+3] = f4.z; sy[c*4+3] = f4.w; sz[c*4+3] = f5.x;
    }
    // swizzled staging: point p = tid*32+i lives at A(p) = (i<<8) + tid  -> conflict-free
#pragma unroll
    for (int i = 0; i < K1_PPT; ++i) {
        int a = (i << 8) + tid;
        lx[a] = sx[i]; ly[a] = sy[i]; lz[a] = sz[i];
        dd[i] = BIGF;
    }
    __syncthreads();

    const int lane = tid & 63;
    const int wid  = tid >> 6;
    unsigned cur = 0;
    float cx = lx[0], cy = ly[0], cz = lz[0];   // coords of point 0 (A(0)=0)

    for (int it = 0; it < NGROUP; ++it) {
        if (tid == 0) fps_idx[b * NGROUP + it] = (int)cur;
        if (it == NGROUP - 1) break;

        // min-update + inline first-max tracking (ascending i == ascending global idx)
        float bestd = -1.0f;
        unsigned besti = 0;
#pragma unroll
        for (int i = 0; i < K1_PPT; ++i) {
            float d = sq_dist(sx[i], sy[i], sz[i], cx, cy, cz);
            dd[i] = fminf(dd[i], d);
            bool gt = dd[i] > bestd;
            bestd = gt ? dd[i] : bestd;
            besti = gt ? (unsigned)i : besti;
        }
        unsigned bestp = (unsigned)tid * K1_PPT + besti;

        // wave argmax: f32 DPP max, then first tied lane (= smallest global index)
        float wm = __int_as_float(rdlane63_i(__float_as_int(wave_fmax(bestd))));
        unsigned long long bal = __ballot(bestd == wm);
        int L = (int)(__ffsll((long long)bal) - 1);
        unsigned widx = (unsigned)__builtin_amdgcn_readlane((int)bestp, L);

        if (lane == 0) {
            int wa = (int)(((widx & 31u) << 8) + (widx >> 5));
            unsigned* pp = part[it & 1][wid];
            pp[0] = 0xFFFFFFFFu - widx;
            pp[1] = __float_as_uint(wm);
            pp[2] = __float_as_uint(lx[wa]);
            pp[3] = __float_as_uint(ly[wa]);
            pp[4] = __float_as_uint(lz[wa]);
        }
        __syncthreads();

        // block reduce over 4 partials: lanes 0..3 hold parts 0..3; max valid in lane 3
        const unsigned* pp = part[it & 1][lane & 3];
        unsigned kl = pp[0], kh = pp[1];
        float xx = __uint_as_float(pp[2]);
        float yy = __uint_as_float(pp[3]);
        float zz = __uint_as_float(pp[4]);
        unsigned long long v = ((unsigned long long)kh << 32) | kl;
        U64_DPP_STEP(0x111, 0xF, >);
        U64_DPP_STEP(0x112, 0xF, >);
        unsigned wkl = (unsigned)__builtin_amdgcn_readlane((int)(unsigned)v, 3);
        cur = 0xFFFFFFFFu - wkl;
        int W = (int)(cur >> 11);   // 2048 pts per wave -> winning wave id
        cx = __int_as_float(__builtin_amdgcn_readlane(__float_as_int(xx), W));
        cy = __int_as_float(__builtin_amdgcn_readlane(__float_as_int(yy), W));
        cz = __int_as_float(__builtin_amdgcn_readlane(__float_as_int(zz), W));
    }
}

// ---------------- Kernel 2: 32-NN per (batch, group) ----------------------------------
extern "C" __global__ __launch_bounds__(K2_THREADS) void knn_kernel(
    const float* __restrict__ xyz, const int* __restrict__ fps_idx,
    float* __restrict__ out)
{
    const int bg  = blockIdx.x;
    const int b   = bg >> 9;
    const int g   = bg & (NGROUP - 1);
    const int tid = threadIdx.x;
    const float* base = xyz + (size_t)b * N_PTS * 6;

    const int q  = fps_idx[b * NGROUP + g];
    const int qq = __builtin_amdgcn_readfirstlane(q);
    const float cx = base[qq * 6 + 0];
    const float cy = base[qq * 6 + 1];
    const float cz = base[qq * 6 + 2];
    const float cn = __fadd_rn(__fadd_rn(__fmul_rn(cx, cx), __fmul_rn(cy, cy)),
                               __fmul_rn(cz, cz));
    const f32x2 cx2 = (f32x2){cx, cx};
    const f32x2 cy2 = (f32x2){cy, cy};
    const f32x2 cz2 = (f32x2){cz, cz};
    const f32x2 cn2 = (f32x2){cn, cn};
    const f32x2 two2 = (f32x2){2.0f, 2.0f};

    const float4* b4 = (const float4*)base;
    const int tb = tid * 24;

    unsigned long long keys[K2_PPT];

#pragma unroll
    for (int c = 0; c < 4; ++c) {
        float4 f0 = b4[tb + c * 6 + 0];
        float4 f1 = b4[tb + c * 6 + 1];
        float4 f2 = b4[tb + c * 6 + 2];
        float4 f3 = b4[tb + c * 6 + 3];
        float4 f4 = b4[tb + c * 6 + 4];
        float4 f5 = b4[tb + c * 6 + 5];
        f32x2 Xa = (f32x2){f0.x, f3.x}, Ya = (f32x2){f0.y, f3.y}, Za = (f32x2){f0.z, f3.z};
        f32x2 Xb = (f32x2){f1.z, f4.z}, Yb = (f32x2){f1.w, f4.w}, Zb = (f32x2){f2.x, f5.x};

#pragma unroll
        for (int h = 0; h < 2; ++h) {
            f32x2 X = h ? Xb : Xa, Y = h ? Yb : Ya, Z = h ? Zb : Za;
            f32x2 xn = pk_add(pk_add(pk_mul(X, X), pk_mul(Y, Y)), pk_mul(Z, Z));
            f32x2 dot = pk_mul(cx2, X);
            dot = pk_fma(cy2, Y, dot);
            dot = pk_fma(cz2, Z, dot);
            f32x2 d2 = pk_add(pk_sub(cn2, pk_mul(two2, dot)), xn);

            int p0 = tid * K2_PPT + c * 4 + h;
            int p1 = p0 + 2;
            keys[c * 4 + h] =
                ((unsigned long long)fxform(__float_as_uint(d2.x)) << 32) | (unsigned)p0;
            keys[c * 4 + h + 2] =
                ((unsigned long long)fxform(__float_as_uint(d2.y)) << 32) | (unsigned)p1;
        }
    }

    // per-thread ascending sort; spill sorted list to LDS (interleaved, conflict-free)
    bitonic_sort<K2_PPT>(keys);

    __shared__ unsigned long long skeys[K2_PPT][K2_THREADS];   // 64 KB
    __shared__ unsigned long long wtop[K2_WAVES][GSIZE];       // 2 KB
#pragma unroll
    for (int i = 0; i < K2_PPT; ++i) skeys[i][tid] = keys[i];

    const int wid  = tid >> 6;
    const int lane = tid & 63;

    // per-wave top-32 extraction: candidate = head of sorted list (regs for head<4,
    // LDS indexed read for the rare deeper heads)
    {
        unsigned long long cand = keys[0];
        unsigned w = 0;
        for (int r = 0; r < GSIZE; ++r) {
            unsigned long long wkey = rdlane_u64(wave_u64_min(cand), 63);
            if (lane == 0) wtop[wid][r] = wkey;
            if (cand == wkey) {   // exactly one lane (keys unique)
                ++w;
                unsigned long long nc;
                if (w == 1)      nc = keys[1];
                else if (w == 2) nc = keys[2];
                else if (w == 3) nc = keys[3];
                else if (w < K2_PPT) nc = skeys[w][tid];   // rare
                else nc = ~0ull;
                cand = nc;
            }
        }
    }
    __syncthreads();
    if (wid != 0) return;

    // wave 0 merges 8 sorted top-32 lists: lane takes 4 consecutive (pre-sorted) elems
    unsigned long long mk0 = wtop[lane >> 3][(lane & 7) * 4 + 0];
    unsigned long long mk1 = wtop[lane >> 3][(lane & 7) * 4 + 1];
    unsigned long long mk2 = wtop[lane >> 3][(lane & 7) * 4 + 2];
    unsigned long long mk3 = wtop[lane >> 3][(lane & 7) * 4 + 3];

    unsigned myp = 0;
    {
        unsigned long long cand = mk0;
        unsigned w = 0;
        for (int r = 0; r < GSIZE; ++r) {
            unsigned long long wkey = rdlane_u64(wave_u64_min(cand), 63);
            if (lane == r) myp = (unsigned)(wkey & 0xFFFFFFFFull);
            if (cand == wkey) {
                ++w;
                cand = (w == 1) ? mk1 : (w == 2) ? mk2 : (w == 3) ? mk3 : ~0ull;
            }
        }
    }

    // ---- outputs (wave 0 only) ----
    const int OFF1 = N_B * NGROUP * GSIZE * 3;   // neigh_attr
    const int OFF2 = 2 * OFF1;                   // center
    const int OFF3 = OFF2 + N_B * NGROUP * 3;    // center_attribute

    if (lane < GSIZE) {
        unsigned p = myp;
        float x  = base[p * 6 + 0];
        float y  = base[p * 6 + 1];
        float z  = base[p * 6 + 2];
        float a0 = base[p * 6 + 3];
        float a1 = base[p * 6 + 4];
        float a2 = base[p * 6 + 5];
        size_t o = ((size_t)(b * NGROUP + g) * GSIZE + lane) * 3;
        out[o + 0] = __fsub_rn(x, cx);
        out[o + 1] = __fsub_rn(y, cy);
        out[o + 2] = __fsub_rn(z, cz);
        out[OFF1 + o + 0] = a0;
        out[OFF1 + o + 1] = a1;
        out[OFF1 + o + 2] = a2;
    } else if (lane == GSIZE) {
        size_t o = (size_t)(b * NGROUP + g) * 3;
        out[OFF2 + o + 0] = cx;
        out[OFF2 + o + 1] = cy;
        out[OFF2 + o + 2] = cz;
        out[OFF3 + o + 0] = base[qq * 6 + 3];
        out[OFF3 + o + 1] = base[qq * 6 + 4];
        out[OFF3 + o + 2] = base[qq * 6 + 5];
    }
}

extern "C" void kernel_launch(void* const* d_in, const int* in_sizes, int n_in,
                              void* d_out, int out_size, void* d_ws, size_t ws_size,
                              hipStream_t stream) {
    const float* xyz = (const float*)d_in[0];
    float* out = (float*)d_out;
    int* fps_idx = (int*)d_ws;   // 8*512 ints = 16 KB

    fps_kernel<<<N_B, K1_THREADS, 0, stream>>>(xyz, fps_idx);
    knn_kernel<<<N_B * NGROUP, K2_THREADS, 0, stream>>>(xyz, fps_idx, out);
}